// Round 4
// baseline (1321.635 us; speedup 1.0000x reference)
//
#include <hip/hip_runtime.h>
#include <math.h>

#define B 16
#define N 2048
#define M 2048
#define BN (B * N)
#define LOG2E 1.4426950408889634f

#define CJ 64             // tile elements per LDS chunk
#define NCH (M / CJ)      // 32 chunks
#define TPB 128           // threads per block (2 waves)
#define RPT 2             // rows (or cols) per thread
#define RBLK (TPB * RPT)  // 256 rows per WG
// grid per sweep: NCH x (N/RBLK) x B = 32 x 8 x 16 = 4096 WGs (8192 waves)

typedef float v2f __attribute__((ext_vector_type(2)));

#define EXP2F(x) __builtin_amdgcn_exp2f(x)
#define SQRTF(x) __builtin_amdgcn_sqrtf(x)

__device__ inline v2f exp2v(v2f a) {
    v2f r;
    r.x = EXP2F(a.x);
    r.y = EXP2F(a.y);
    return r;
}

// ---------------------------------------------------------------------------
// init (ws re-poisoned every call): rl[0]=1, rr[0]=1, rs0=rs2=0, t1[1]=0,
// ss2[0]=0, cost=0. Other buffers are zeroed/written by the sweep kernels'
// maintenance duties before first read.
// ---------------------------------------------------------------------------
__global__ __launch_bounds__(256) void k_init(float* __restrict__ rl0,
                                              float* __restrict__ rr0,
                                              float* __restrict__ rs0,
                                              float* __restrict__ rs2,
                                              float* __restrict__ t1b,
                                              float* __restrict__ ss20,
                                              float* __restrict__ cost) {
    int idx = blockIdx.x * 256 + threadIdx.x;
    rl0[idx] = 1.0f;
    rr0[idx] = 1.0f;
    rs0[idx] = 0.0f;
    rs2[idx] = 0.0f;
    t1b[idx] = 0.0f;
    ss20[idx] = 0.0f;
    if (idx < B) cost[idx] = 0.0f;
}

// ---------------------------------------------------------------------------
// rowsum for level 0 (rr==1, rl==1): rs[i] += sum_j exp2(c2*d2(i,j))
// scaled dot form: arg = c2*ni + c2*nj - 2c2<xi,xj>
// ---------------------------------------------------------------------------
__global__ __launch_bounds__(TPB) void k_rowsum0(const float* __restrict__ xyz1,
                                                 const float* __restrict__ xyz2,
                                                 float* __restrict__ rs,
                                                 float c2) {
    __shared__ float4 tile4[CJ];  // xj, yj, zj, c2*|xj|^2
    const int b = blockIdx.z;
    const int tx = threadIdx.x;
    const int i0 = blockIdx.y * RBLK + tx;
    const int i1 = i0 + TPB;

    if (tx < CJ) {
        int j = blockIdx.x * CJ + tx;
        const float* p = xyz2 + 3 * ((size_t)b * M + j);
        float x = p[0], y = p[1], z = p[2];
        float nj = c2 * fmaf(x, x, fmaf(y, y, z * z));
        tile4[tx] = make_float4(x, y, z, nj);
    }
    __syncthreads();

    const float* pa = xyz1 + 3 * ((size_t)b * N + i0);
    const float* pb = xyz1 + 3 * ((size_t)b * N + i1);
    const float m2c2 = -2.0f * c2;
    v2f Xp, Yp, Zp, nip;
    Xp.x = m2c2 * pa[0]; Xp.y = m2c2 * pb[0];
    Yp.x = m2c2 * pa[1]; Yp.y = m2c2 * pb[1];
    Zp.x = m2c2 * pa[2]; Zp.y = m2c2 * pb[2];
    nip.x = c2 * fmaf(pa[0], pa[0], fmaf(pa[1], pa[1], pa[2] * pa[2]));
    nip.y = c2 * fmaf(pb[0], pb[0], fmaf(pb[1], pb[1], pb[2] * pb[2]));

    v2f acc = {0.0f, 0.0f};
#pragma unroll 8
    for (int t = 0; t < CJ; ++t) {
        float4 q4 = tile4[t];
        v2f arg = q4.x * Xp + (q4.y * Yp + (q4.z * Zp + (nip + q4.w)));
        acc += exp2v(arg);
    }
    atomicAdd(&rs[b * N + i0], acc.x);
    atomicAdd(&rs[b * N + i1], acc.y);
}

// ---------------------------------------------------------------------------
// Column sweep (level l) + folded "k_post" of level l-1:
// tile element i: rl_new = max(rl_old - (rl_old/(rs_prev+1e-9))*t1_in, 0);
//                 a = rl_new/(rs_cur+1e-9); duties (y==0): write rl_out,
//                 zero t1_zero and rs_zero for this level's fused.
// thread (2 cols j): ss2[j] += rr[j] * sum_i exp2(c2*d2)*a[i]
// ZL: c2==0 -> exp==1.
// ---------------------------------------------------------------------------
template <bool ZL>
__global__ __launch_bounds__(TPB) void k_colsum(const float* __restrict__ xyz1,
                                                const float* __restrict__ xyz2,
                                                const float* __restrict__ rl_in,
                                                float* __restrict__ rl_out,
                                                const float* __restrict__ rs_prev,
                                                const float* __restrict__ rs_cur,
                                                float* __restrict__ rs_zero,
                                                const float* __restrict__ t1_in,
                                                float* __restrict__ t1_zero,
                                                const float* __restrict__ rr,
                                                float* __restrict__ ss2_acc,
                                                float c2) {
    __shared__ float4 tile4[CJ];  // xi, yi, zi, c2*|xi|^2
    __shared__ float tileA[CJ];   // a_i
    const int b = blockIdx.z;
    const int tx = threadIdx.x;
    const int j0 = blockIdx.y * RBLK + tx;
    const int j1 = j0 + TPB;

    if (tx < CJ) {
        int i = blockIdx.x * CJ + tx;
        int gi = b * N + i;
        float rlo = rl_in[gi];
        float ap = rlo / (rs_prev[gi] + 1e-9f);
        float rln = fmaxf(rlo - ap * t1_in[gi], 0.0f);
        float a = rln / (rs_cur[gi] + 1e-9f);
        const float* p = xyz1 + 3 * (size_t)gi;
        float x = p[0], y = p[1], z = p[2];
        float ni = c2 * fmaf(x, x, fmaf(y, y, z * z));
        tile4[tx] = make_float4(x, y, z, ni);
        tileA[tx] = a;
        if (blockIdx.y == 0) {
            rl_out[gi] = rln;
            t1_zero[gi] = 0.0f;
            rs_zero[gi] = 0.0f;
        }
    }
    __syncthreads();

    const int gj0 = b * M + j0;
    const int gj1 = b * M + j1;

    if (ZL) {
        float sacc = 0.0f;
#pragma unroll 8
        for (int t = 0; t < CJ; ++t) sacc += tileA[t];
        atomicAdd(&ss2_acc[gj0], sacc * rr[gj0]);
        atomicAdd(&ss2_acc[gj1], sacc * rr[gj1]);
        return;
    }

    const float* pa = xyz2 + 3 * (size_t)gj0;
    const float* pb = xyz2 + 3 * (size_t)gj1;
    const float m2c2 = -2.0f * c2;
    v2f Xp, Yp, Zp, njp;
    Xp.x = m2c2 * pa[0]; Xp.y = m2c2 * pb[0];
    Yp.x = m2c2 * pa[1]; Yp.y = m2c2 * pb[1];
    Zp.x = m2c2 * pa[2]; Zp.y = m2c2 * pb[2];
    njp.x = c2 * fmaf(pa[0], pa[0], fmaf(pa[1], pa[1], pa[2] * pa[2]));
    njp.y = c2 * fmaf(pb[0], pb[0], fmaf(pb[1], pb[1], pb[2] * pb[2]));

    v2f acc = {0.0f, 0.0f};
#pragma unroll 8
    for (int t = 0; t < CJ; ++t) {
        float4 q4 = tile4[t];
        v2f arg = q4.x * Xp + (q4.y * Yp + (q4.z * Zp + (njp + q4.w)));
        acc += exp2v(arg) * tileA[t];
    }
    atomicAdd(&ss2_acc[gj0], acc.x * rr[gj0]);
    atomicAdd(&ss2_acc[gj1], acc.y * rr[gj1]);
}

// ---------------------------------------------------------------------------
// Fused finrow(l) + rowsum(l+1).
// tile element j: s=min(rr/(ss2+1e-9),1); q=rr*s; rrn=max(rr-ss2*s,0);
//   duties (y==0): rr_out[j]=rrn, zero ss2_zero[j] (for next colsum).
// thread (2 rows i): arg = cS*d2 (scaled dot form).
//   MODE 0 (l=0..7): cS=c2[l+1]; en=exp2(arg); el=en^4
//   MODE 1 (l=8):    cS=c2[8];   el=exp2(arg); en=1
//   MODE 2 (l=9):    cS=1;       el=1 (arg==d2); no rs/t1/rr_out
//   d2 = arg*invS; T1+=el*q; T2+=el*q*sqrt(max(d2,1e-12)); rs+=en*rrn
// epilogue: t1[i]+=T1; rs_next[i]+=rs; cost[b]+=a[i]*T2.
// ---------------------------------------------------------------------------
template <int MODE>
__global__ __launch_bounds__(TPB) void k_fused(const float* __restrict__ xyz1,
                                               const float* __restrict__ xyz2,
                                               const float* __restrict__ rr_in,
                                               float* __restrict__ rr_out,
                                               const float* __restrict__ ss2_in,
                                               float* __restrict__ ss2_zero,
                                               const float* __restrict__ rl_new,
                                               const float* __restrict__ rs_cur,
                                               float* __restrict__ rs_next,
                                               float* __restrict__ t1_acc,
                                               float* __restrict__ cost,
                                               float cS, float invS) {
    __shared__ float4 tile4[CJ];  // xj, yj, zj, q
    __shared__ float2 tile2[CJ];  // rrn, cS*|xj|^2
    const int b = blockIdx.z;
    const int tx = threadIdx.x;
    const int i0 = blockIdx.y * RBLK + tx;
    const int i1 = i0 + TPB;

    if (tx < CJ) {
        int j = blockIdx.x * CJ + tx;
        int gj = b * M + j;
        float rrv = rr_in[gj];
        float sv = ss2_in[gj];
        float s = fminf(rrv / (sv + 1e-9f), 1.0f);
        float q = rrv * s;
        float rrn = fmaxf(rrv - sv * s, 0.0f);
        const float* p = xyz2 + 3 * (size_t)gj;
        float x = p[0], y = p[1], z = p[2];
        float nj = cS * fmaf(x, x, fmaf(y, y, z * z));
        tile4[tx] = make_float4(x, y, z, q);
        tile2[tx] = make_float2(rrn, nj);
        if (MODE != 2 && blockIdx.y == 0) {
            rr_out[gj] = rrn;
            ss2_zero[gj] = 0.0f;
        }
    }
    __syncthreads();

    const float* pa = xyz1 + 3 * ((size_t)b * N + i0);
    const float* pb = xyz1 + 3 * ((size_t)b * N + i1);
    const float m2c = -2.0f * cS;
    v2f Xp, Yp, Zp, nip;
    Xp.x = m2c * pa[0]; Xp.y = m2c * pb[0];
    Yp.x = m2c * pa[1]; Yp.y = m2c * pb[1];
    Zp.x = m2c * pa[2]; Zp.y = m2c * pb[2];
    nip.x = cS * fmaf(pa[0], pa[0], fmaf(pa[1], pa[1], pa[2] * pa[2]));
    nip.y = cS * fmaf(pb[0], pb[0], fmaf(pb[1], pb[1], pb[2] * pb[2]));

    v2f T1 = {0.0f, 0.0f}, T2 = {0.0f, 0.0f}, rs = {0.0f, 0.0f};
#pragma unroll 8
    for (int t = 0; t < CJ; ++t) {
        float4 q4 = tile4[t];
        float2 rn = tile2[t];
        v2f arg = q4.x * Xp + (q4.y * Yp + (q4.z * Zp + (nip + rn.y)));
        v2f el, en;
        if (MODE == 0) {
            en = exp2v(arg);
            v2f e2 = en * en;
            el = e2 * e2;
        } else if (MODE == 1) {
            el = exp2v(arg);
        }
        v2f d2 = arg * invS;
        d2.x = fmaxf(d2.x, 1e-12f);
        d2.y = fmaxf(d2.y, 1e-12f);
        v2f sd;
        sd.x = SQRTF(d2.x);
        sd.y = SQRTF(d2.y);
        v2f wq;
        if (MODE == 2) {
            wq.x = q4.w;
            wq.y = q4.w;
        } else {
            wq = el * q4.w;
        }
        T1 += wq;
        T2 += wq * sd;
        if (MODE == 0)
            rs += en * rn.x;
        else if (MODE == 1)
            rs += rn.x;
    }

    const int gi0 = b * N + i0;
    const int gi1 = b * N + i1;
    if (MODE != 2) {
        atomicAdd(&t1_acc[gi0], T1.x);
        atomicAdd(&t1_acc[gi1], T1.y);
        atomicAdd(&rs_next[gi0], rs.x);
        atomicAdd(&rs_next[gi1], rs.y);
    }

    float aa = rl_new[gi0] / (rs_cur[gi0] + 1e-9f);
    float ab = rl_new[gi1] / (rs_cur[gi1] + 1e-9f);
    float contrib = fmaf(aa, T2.x, ab * T2.y);
#pragma unroll
    for (int off = 32; off > 0; off >>= 1)
        contrib += __shfl_down(contrib, off, 64);
    if ((threadIdx.x & 63) == 0) atomicAdd(&cost[b], contrib);
}

extern "C" void kernel_launch(void* const* d_in, const int* in_sizes, int n_in,
                              void* d_out, int out_size, void* d_ws, size_t ws_size,
                              hipStream_t stream) {
    const float* xyz1 = (const float*)d_in[0];
    const float* xyz2 = (const float*)d_in[1];
    float* cost = (float*)d_out;

    float* ws = (float*)d_ws;
    float* rl[2] = {ws + 0 * BN, ws + 1 * BN};
    float* rr[2] = {ws + 2 * BN, ws + 3 * BN};
    float* rs[3] = {ws + 4 * BN, ws + 5 * BN, ws + 6 * BN};
    float* ss2b[2] = {ws + 7 * BN, ws + 8 * BN};
    float* t1[2] = {ws + 9 * BN, ws + 10 * BN};

    static const float levels[10] = {-16384.0f, -4096.0f, -1024.0f, -256.0f,
                                     -64.0f,    -16.0f,   -4.0f,    -1.0f,
                                     -0.25f,    0.0f};
    float c2[10];
    for (int l = 0; l < 10; ++l) c2[l] = levels[l] * LOG2E;

    dim3 grid(NCH, N / RBLK, B);  // 32 x 8 x 16 = 4096 WGs
    dim3 blk(TPB);

    k_init<<<dim3(BN / 256), dim3(256), 0, stream>>>(rl[0], rr[0], rs[0], rs[2],
                                                     t1[1], ss2b[0], cost);
    k_rowsum0<<<grid, blk, 0, stream>>>(xyz1, xyz2, rs[0], c2[0]);

    for (int l = 0; l < 10; ++l) {
        int p = l & 1;
        // colsum(l): reads rs[(l+2)%3] (prev), rs[l%3] (cur), t1[1-p] (prev),
        // zeroes rs[(l+1)%3], t1[p]; rl[p] -> rl[1-p]; ss2 accum into ss2b[p].
        if (l == 9)
            k_colsum<true><<<grid, blk, 0, stream>>>(
                xyz1, xyz2, rl[p], rl[1 - p], rs[(l + 2) % 3], rs[l % 3],
                rs[(l + 1) % 3], t1[1 - p], t1[p], rr[p], ss2b[p], c2[l]);
        else
            k_colsum<false><<<grid, blk, 0, stream>>>(
                xyz1, xyz2, rl[p], rl[1 - p], rs[(l + 2) % 3], rs[l % 3],
                rs[(l + 1) % 3], t1[1 - p], t1[p], rr[p], ss2b[p], c2[l]);

        // fused(l): rr[p] -> rr[1-p]; reads ss2b[p], zeroes ss2b[1-p];
        // reads rl[1-p], rs[l%3]; accumulates rs[(l+1)%3], t1[p], cost.
        if (l <= 7) {
            float cS = c2[l + 1];
            k_fused<0><<<grid, blk, 0, stream>>>(
                xyz1, xyz2, rr[p], rr[1 - p], ss2b[p], ss2b[1 - p], rl[1 - p],
                rs[l % 3], rs[(l + 1) % 3], t1[p], cost, cS, 1.0f / cS);
        } else if (l == 8) {
            float cS = c2[8];
            k_fused<1><<<grid, blk, 0, stream>>>(
                xyz1, xyz2, rr[p], rr[1 - p], ss2b[p], ss2b[1 - p], rl[1 - p],
                rs[l % 3], rs[(l + 1) % 3], t1[p], cost, cS, 1.0f / cS);
        } else {
            k_fused<2><<<grid, blk, 0, stream>>>(
                xyz1, xyz2, rr[p], rr[1 - p], ss2b[p], ss2b[1 - p], rl[1 - p],
                rs[l % 3], rs[(l + 1) % 3], t1[p], cost, 1.0f, 1.0f);
        }
    }
}

// Round 5
// 646.290 us; speedup vs baseline: 2.0450x; 2.0450x over previous
//
#include <hip/hip_runtime.h>
#include <math.h>

#define B 16
#define N 2048
#define M 2048
#define BN (B * N)
#define LOG2E 1.4426950408889634f

#define CJ 256            // tile elements per LDS chunk
#define NCH (M / CJ)      // 8 chunks
#define TPB 128           // threads per block (2 waves)
#define RPT 2             // rows (or cols) per thread
#define RBLK (TPB * RPT)  // 256 rows per WG
// sweep grid: (NCH, N/RBLK, B) = (8, 8, 16) = 1024 WGs, 2048 waves (2/SIMD)

typedef float v2f __attribute__((ext_vector_type(2)));

#define EXP2F(x) __builtin_amdgcn_exp2f(x)
#define SQRTF(x) __builtin_amdgcn_sqrtf(x)

__device__ inline v2f exp2v(v2f a) {
    v2f r;
    r.x = EXP2F(a.x);
    r.y = EXP2F(a.y);
    return r;
}

// ---------------------------------------------------------------------------
// Pack xyz (stride-3) into float4 (x,y,z,|p|^2). 2*BN threads.
// ---------------------------------------------------------------------------
__global__ __launch_bounds__(256) void k_pack(const float* __restrict__ xyz1,
                                              const float* __restrict__ xyz2,
                                              float4* __restrict__ p1,
                                              float4* __restrict__ p2) {
    int idx = blockIdx.x * 256 + threadIdx.x;
    const float* s = (idx < BN) ? (xyz1 + 3 * (size_t)idx)
                                : (xyz2 + 3 * (size_t)(idx - BN));
    float x = s[0], y = s[1], z = s[2];
    float n = fmaf(x, x, fmaf(y, y, z * z));
    float4 v = make_float4(x, y, z, n);
    if (idx < BN) p1[idx] = v;
    else p2[idx - BN] = v;
}

// ---------------------------------------------------------------------------
// init: rl[0]=1, rr[0]=1, rs0=rs2=0, t1[1]=0, ss2[0]=0, cost=0.
// (ws/d_out re-poisoned before every call.)
// ---------------------------------------------------------------------------
__global__ __launch_bounds__(256) void k_init(float* __restrict__ rl0,
                                              float* __restrict__ rr0,
                                              float* __restrict__ rs0,
                                              float* __restrict__ rs2,
                                              float* __restrict__ t1b,
                                              float* __restrict__ ss20,
                                              float* __restrict__ cost) {
    int idx = blockIdx.x * 256 + threadIdx.x;
    rl0[idx] = 1.0f;
    rr0[idx] = 1.0f;
    rs0[idx] = 0.0f;
    rs2[idx] = 0.0f;
    t1b[idx] = 0.0f;
    ss20[idx] = 0.0f;
    if (idx < B) cost[idx] = 0.0f;
}

// ---------------------------------------------------------------------------
// rowsum for level 0 (rr==1): rs[i] += sum_j exp2(c2*d2(i,j))
// ---------------------------------------------------------------------------
__global__ __launch_bounds__(TPB) void k_rowsum0(const float4* __restrict__ p1,
                                                 const float4* __restrict__ p2,
                                                 float* __restrict__ rs,
                                                 float c2) {
    __shared__ float4 tile4[CJ];  // xj, yj, zj, c2*nj
    const int b = blockIdx.z;
    const int tx = threadIdx.x;
    const int i0 = blockIdx.y * RBLK + tx;
    const int i1 = i0 + TPB;

    for (int t = tx; t < CJ; t += TPB) {
        int gj = b * M + blockIdx.x * CJ + t;
        float4 f = p2[gj];
        tile4[t] = make_float4(f.x, f.y, f.z, c2 * f.w);
    }
    __syncthreads();

    float4 fa = p1[b * N + i0];
    float4 fb = p1[b * N + i1];
    const float m2c = -2.0f * c2;
    v2f Xp = {m2c * fa.x, m2c * fb.x};
    v2f Yp = {m2c * fa.y, m2c * fb.y};
    v2f Zp = {m2c * fa.z, m2c * fb.z};
    v2f nip = {c2 * fa.w, c2 * fb.w};

    v2f acc = {0.0f, 0.0f};
#pragma unroll 8
    for (int t = 0; t < CJ; ++t) {
        float4 q4 = tile4[t];
        v2f arg = q4.x * Xp + (q4.y * Yp + (q4.z * Zp + (nip + q4.w)));
        acc += exp2v(arg);
    }
    atomicAdd(&rs[b * N + i0], acc.x);
    atomicAdd(&rs[b * N + i1], acc.y);
}

// ---------------------------------------------------------------------------
// Column sweep (level l) + folded rl-update of level l-1 (tile phase):
// tile elem i: rl_new = max(rl_old - (rl_old/(rs_prev+eps))*t1_in, 0);
//              a = rl_new/(rs_cur+eps); duties (y==0): rl_out, zero t1/rs.
// thread (2 cols j): ss2[j] += rr[j] * sum_i exp2(cS*d2)*a[i]
// ---------------------------------------------------------------------------
__global__ __launch_bounds__(TPB) void k_colsum(const float4* __restrict__ p1,
                                                const float4* __restrict__ p2,
                                                const float* __restrict__ rl_in,
                                                float* __restrict__ rl_out,
                                                const float* __restrict__ rs_prev,
                                                const float* __restrict__ rs_cur,
                                                float* __restrict__ rs_zero,
                                                const float* __restrict__ t1_in,
                                                float* __restrict__ t1_zero,
                                                const float* __restrict__ rr,
                                                float* __restrict__ ss2_acc,
                                                float cS) {
    __shared__ float4 tile4[CJ];  // xi, yi, zi, cS*ni
    __shared__ float tileA[CJ];   // a_i
    const int b = blockIdx.z;
    const int tx = threadIdx.x;
    const int j0 = blockIdx.y * RBLK + tx;
    const int j1 = j0 + TPB;

    for (int t = tx; t < CJ; t += TPB) {
        int gi = b * N + blockIdx.x * CJ + t;
        float4 f = p1[gi];
        float rlo = rl_in[gi];
        float ap = rlo / (rs_prev[gi] + 1e-9f);
        float rln = fmaxf(rlo - ap * t1_in[gi], 0.0f);
        float a = rln / (rs_cur[gi] + 1e-9f);
        tile4[t] = make_float4(f.x, f.y, f.z, cS * f.w);
        tileA[t] = a;
        if (blockIdx.y == 0) {
            rl_out[gi] = rln;
            t1_zero[gi] = 0.0f;
            rs_zero[gi] = 0.0f;
        }
    }
    __syncthreads();

    const int gj0 = b * M + j0;
    const int gj1 = b * M + j1;
    float4 fa = p2[gj0];
    float4 fb = p2[gj1];
    const float m2c = -2.0f * cS;
    v2f Xp = {m2c * fa.x, m2c * fb.x};
    v2f Yp = {m2c * fa.y, m2c * fb.y};
    v2f Zp = {m2c * fa.z, m2c * fb.z};
    v2f njp = {cS * fa.w, cS * fb.w};

    v2f acc = {0.0f, 0.0f};
#pragma unroll 8
    for (int t = 0; t < CJ; ++t) {
        float4 q4 = tile4[t];
        v2f arg = q4.x * Xp + (q4.y * Yp + (q4.z * Zp + (njp + q4.w)));
        acc += exp2v(arg) * tileA[t];
    }
    atomicAdd(&ss2_acc[gj0], acc.x * rr[gj0]);
    atomicAdd(&ss2_acc[gj1], acc.y * rr[gj1]);
}

// ---------------------------------------------------------------------------
// Level-9 colsum, part 1 (exp==1): per-batch S = sum_i a_i, plus the folded
// rl-update of level 8. Grid: B WGs x 256 threads.
// ---------------------------------------------------------------------------
__global__ __launch_bounds__(256) void k_suma(const float* __restrict__ rl_in,
                                              float* __restrict__ rl_out,
                                              const float* __restrict__ rs_prev,
                                              const float* __restrict__ rs_cur,
                                              const float* __restrict__ t1_in,
                                              float* __restrict__ S) {
    __shared__ float red[4];
    const int b = blockIdx.x;
    const int tx = threadIdx.x;
    float s = 0.0f;
#pragma unroll
    for (int k = 0; k < N / 256; ++k) {
        int gi = b * N + k * 256 + tx;
        float rlo = rl_in[gi];
        float ap = rlo / (rs_prev[gi] + 1e-9f);
        float rln = fmaxf(rlo - ap * t1_in[gi], 0.0f);
        rl_out[gi] = rln;
        s += rln / (rs_cur[gi] + 1e-9f);
    }
#pragma unroll
    for (int off = 32; off > 0; off >>= 1)
        s += __shfl_down(s, off, 64);
    if ((tx & 63) == 0) red[tx >> 6] = s;
    __syncthreads();
    if (tx == 0) S[b] = red[0] + red[1] + red[2] + red[3];
}

// Level-9 colsum, part 2: ss2[j] = rr[j] * S[b]  (direct store)
__global__ __launch_bounds__(256) void k_mulss2(const float* __restrict__ rr,
                                                const float* __restrict__ S,
                                                float* __restrict__ ss2_out) {
    int idx = blockIdx.x * 256 + threadIdx.x;
    ss2_out[idx] = rr[idx] * S[idx >> 11];
}

// ---------------------------------------------------------------------------
// Fused finrow(l) + rowsum(l+1).
// tile elem j: s=min(rr/(ss2+eps),1); q=rr*s; rrn=max(rr-ss2*s,0);
//   duties (y==0): rr_out[j]=rrn, zero ss2_zero[j].
// thread (2 rows i), arg = cS*d2 via scaled dot form:
//   MODE 0 (l=0..7): cS=c2[l+1]; en=exp2(arg); el=en^4
//   MODE 1 (l=8):    cS=c2[8];   el=exp2(arg); en=1
//   MODE 2 (l=9):    cS=1 (arg==d2); el=1; no rs/t1/rr_out
//   d2=arg*invS; T1+=el*q; T2+=el*q*sqrt(max(d2,1e-12)); rs+=en*rrn
// epilogue: t1[i]+=T1; rs_next[i]+=rs; cost[b]+=a[i]*T2.
// ---------------------------------------------------------------------------
template <int MODE>
__global__ __launch_bounds__(TPB) void k_fused(const float4* __restrict__ p1,
                                               const float4* __restrict__ p2,
                                               const float* __restrict__ rr_in,
                                               float* __restrict__ rr_out,
                                               const float* __restrict__ ss2_in,
                                               float* __restrict__ ss2_zero,
                                               const float* __restrict__ rl_new,
                                               const float* __restrict__ rs_cur,
                                               float* __restrict__ rs_next,
                                               float* __restrict__ t1_acc,
                                               float* __restrict__ cost,
                                               float cS, float invS) {
    __shared__ float4 tile4[CJ];  // xj, yj, zj, q
    __shared__ float2 tile2[CJ];  // rrn, cS*nj
    const int b = blockIdx.z;
    const int tx = threadIdx.x;
    const int i0 = blockIdx.y * RBLK + tx;
    const int i1 = i0 + TPB;

    for (int t = tx; t < CJ; t += TPB) {
        int gj = b * M + blockIdx.x * CJ + t;
        float4 f = p2[gj];
        float rrv = rr_in[gj];
        float sv = ss2_in[gj];
        float s = fminf(rrv / (sv + 1e-9f), 1.0f);
        float q = rrv * s;
        float rrn = fmaxf(rrv - sv * s, 0.0f);
        tile4[t] = make_float4(f.x, f.y, f.z, q);
        tile2[t] = make_float2(rrn, cS * f.w);
        if (MODE != 2 && blockIdx.y == 0) {
            rr_out[gj] = rrn;
            ss2_zero[gj] = 0.0f;
        }
    }
    __syncthreads();

    float4 fa = p1[b * N + i0];
    float4 fb = p1[b * N + i1];
    const float m2c = -2.0f * cS;
    v2f Xp = {m2c * fa.x, m2c * fb.x};
    v2f Yp = {m2c * fa.y, m2c * fb.y};
    v2f Zp = {m2c * fa.z, m2c * fb.z};
    v2f nip = {cS * fa.w, cS * fb.w};

    v2f T1 = {0.0f, 0.0f}, T2 = {0.0f, 0.0f}, rs = {0.0f, 0.0f};
#pragma unroll 8
    for (int t = 0; t < CJ; ++t) {
        float4 q4 = tile4[t];
        float2 rn = tile2[t];
        v2f arg = q4.x * Xp + (q4.y * Yp + (q4.z * Zp + (nip + rn.y)));
        v2f el, en;
        if (MODE == 0) {
            en = exp2v(arg);
            v2f e2 = en * en;
            el = e2 * e2;
        } else if (MODE == 1) {
            el = exp2v(arg);
        }
        v2f d2 = arg * invS;
        d2.x = fmaxf(d2.x, 1e-12f);
        d2.y = fmaxf(d2.y, 1e-12f);
        v2f sd;
        sd.x = SQRTF(d2.x);
        sd.y = SQRTF(d2.y);
        v2f wq;
        if (MODE == 2) {
            wq.x = q4.w;
            wq.y = q4.w;
        } else {
            wq = el * q4.w;
        }
        T1 += wq;
        T2 += wq * sd;
        if (MODE == 0)
            rs += en * rn.x;
        else if (MODE == 1)
            rs += rn.x;
    }

    const int gi0 = b * N + i0;
    const int gi1 = b * N + i1;
    if (MODE != 2) {
        atomicAdd(&t1_acc[gi0], T1.x);
        atomicAdd(&t1_acc[gi1], T1.y);
        atomicAdd(&rs_next[gi0], rs.x);
        atomicAdd(&rs_next[gi1], rs.y);
    }

    float aa = rl_new[gi0] / (rs_cur[gi0] + 1e-9f);
    float ab = rl_new[gi1] / (rs_cur[gi1] + 1e-9f);
    float contrib = fmaf(aa, T2.x, ab * T2.y);
#pragma unroll
    for (int off = 32; off > 0; off >>= 1)
        contrib += __shfl_down(contrib, off, 64);
    if ((threadIdx.x & 63) == 0) atomicAdd(&cost[b], contrib);
}

extern "C" void kernel_launch(void* const* d_in, const int* in_sizes, int n_in,
                              void* d_out, int out_size, void* d_ws, size_t ws_size,
                              hipStream_t stream) {
    const float* xyz1 = (const float*)d_in[0];
    const float* xyz2 = (const float*)d_in[1];
    float* cost = (float*)d_out;

    float* ws = (float*)d_ws;
    float* rl[2] = {ws + 0 * BN, ws + 1 * BN};
    float* rr[2] = {ws + 2 * BN, ws + 3 * BN};
    float* rs[3] = {ws + 4 * BN, ws + 5 * BN, ws + 6 * BN};
    float* ss2b[2] = {ws + 7 * BN, ws + 8 * BN};
    float* t1[2] = {ws + 9 * BN, ws + 10 * BN};
    float4* p1 = (float4*)(ws + 11 * BN);
    float4* p2 = (float4*)(ws + 15 * BN);
    float* S = ws + 19 * BN;

    static const float levels[10] = {-16384.0f, -4096.0f, -1024.0f, -256.0f,
                                     -64.0f,    -16.0f,   -4.0f,    -1.0f,
                                     -0.25f,    0.0f};
    float c2[10];
    for (int l = 0; l < 10; ++l) c2[l] = levels[l] * LOG2E;

    dim3 grid(NCH, N / RBLK, B);  // (8, 8, 16) = 1024 WGs
    dim3 blk(TPB);

    k_pack<<<dim3(2 * BN / 256), dim3(256), 0, stream>>>(xyz1, xyz2, p1, p2);
    k_init<<<dim3(BN / 256), dim3(256), 0, stream>>>(rl[0], rr[0], rs[0], rs[2],
                                                     t1[1], ss2b[0], cost);
    k_rowsum0<<<grid, blk, 0, stream>>>(p1, p2, rs[0], c2[0]);

    for (int l = 0; l < 10; ++l) {
        int p = l & 1;
        if (l < 9) {
            // colsum(l): reads rs[(l+2)%3] (prev), rs[l%3] (cur), t1[1-p];
            // zeroes rs[(l+1)%3], t1[p]; rl[p]->rl[1-p]; accum ss2b[p].
            k_colsum<<<grid, blk, 0, stream>>>(
                p1, p2, rl[p], rl[1 - p], rs[(l + 2) % 3], rs[l % 3],
                rs[(l + 1) % 3], t1[1 - p], t1[p], rr[p], ss2b[p], c2[l]);
        } else {
            // level 9: exp==1 -> ss2 = rr * sum_i a_i
            k_suma<<<dim3(B), dim3(256), 0, stream>>>(
                rl[p], rl[1 - p], rs[(l + 2) % 3], rs[l % 3], t1[1 - p], S);
            k_mulss2<<<dim3(BN / 256), dim3(256), 0, stream>>>(rr[p], S, ss2b[p]);
        }

        // fused(l): rr[p]->rr[1-p]; reads ss2b[p], zeroes ss2b[1-p];
        // reads rl[1-p], rs[l%3]; accumulates rs[(l+1)%3], t1[p], cost.
        if (l <= 7) {
            float cS = c2[l + 1];
            k_fused<0><<<grid, blk, 0, stream>>>(
                p1, p2, rr[p], rr[1 - p], ss2b[p], ss2b[1 - p], rl[1 - p],
                rs[l % 3], rs[(l + 1) % 3], t1[p], cost, cS, 1.0f / cS);
        } else if (l == 8) {
            float cS = c2[8];
            k_fused<1><<<grid, blk, 0, stream>>>(
                p1, p2, rr[p], rr[1 - p], ss2b[p], ss2b[1 - p], rl[1 - p],
                rs[l % 3], rs[(l + 1) % 3], t1[p], cost, cS, 1.0f / cS);
        } else {
            k_fused<2><<<grid, blk, 0, stream>>>(
                p1, p2, rr[p], rr[1 - p], ss2b[p], ss2b[1 - p], rl[1 - p],
                rs[l % 3], rs[(l + 1) % 3], t1[p], cost, 1.0f, 1.0f);
        }
    }
}

// Round 6
// 610.767 us; speedup vs baseline: 2.1639x; 1.0582x over previous
//
#include <hip/hip_runtime.h>
#include <math.h>

#define B 16
#define N 2048
#define M 2048
#define BN (B * N)
#define LOG2E 1.4426950408889634f

#define CJ 128            // tile elements per LDS chunk
#define NCH (M / CJ)      // 16 chunks
#define TPB 128           // threads per block (2 waves)
#define RPT 4             // rows (or cols) per thread
#define RBLK (TPB * RPT)  // 512 rows per WG
// sweep grid: (NCH, N/RBLK, B) = (16, 4, 16) = 1024 WGs, 2048 waves (2/SIMD)

typedef float v2f __attribute__((ext_vector_type(2)));

#define EXP2F(x) __builtin_amdgcn_exp2f(x)
#define SQRTF(x) __builtin_amdgcn_sqrtf(x)

__device__ inline v2f exp2v(v2f a) {
    v2f r;
    r.x = EXP2F(a.x);
    r.y = EXP2F(a.y);
    return r;
}

// ---------------------------------------------------------------------------
// Pack xyz (stride-3) into float4 (x,y,z,|p|^2). 2*BN threads.
// ---------------------------------------------------------------------------
__global__ __launch_bounds__(256) void k_pack(const float* __restrict__ xyz1,
                                              const float* __restrict__ xyz2,
                                              float4* __restrict__ p1,
                                              float4* __restrict__ p2) {
    int idx = blockIdx.x * 256 + threadIdx.x;
    const float* s = (idx < BN) ? (xyz1 + 3 * (size_t)idx)
                                : (xyz2 + 3 * (size_t)(idx - BN));
    float x = s[0], y = s[1], z = s[2];
    float n = fmaf(x, x, fmaf(y, y, z * z));
    float4 v = make_float4(x, y, z, n);
    if (idx < BN) p1[idx] = v;
    else p2[idx - BN] = v;
}

// ---------------------------------------------------------------------------
// init: rl[0]=1, rr[0]=1, rs0=rs2=0, t1[1]=0, ss2[0]=0, cost=0.
// ---------------------------------------------------------------------------
__global__ __launch_bounds__(256) void k_init(float* __restrict__ rl0,
                                              float* __restrict__ rr0,
                                              float* __restrict__ rs0,
                                              float* __restrict__ rs2,
                                              float* __restrict__ t1b,
                                              float* __restrict__ ss20,
                                              float* __restrict__ cost) {
    int idx = blockIdx.x * 256 + threadIdx.x;
    rl0[idx] = 1.0f;
    rr0[idx] = 1.0f;
    rs0[idx] = 0.0f;
    rs2[idx] = 0.0f;
    t1b[idx] = 0.0f;
    ss20[idx] = 0.0f;
    if (idx < B) cost[idx] = 0.0f;
}

// ---------------------------------------------------------------------------
// rowsum for level 0 (rr==1): rs[i] += sum_j exp2(c2*d2(i,j))
// 4 rows/thread as two v2f chains.
// ---------------------------------------------------------------------------
__global__ __launch_bounds__(TPB, 2) void k_rowsum0(const float4* __restrict__ p1,
                                                    const float4* __restrict__ p2,
                                                    float* __restrict__ rs,
                                                    float c2) {
    __shared__ float4 tile4[CJ];  // xj, yj, zj, c2*nj
    const int b = blockIdx.z;
    const int tx = threadIdx.x;
    const int i0 = blockIdx.y * RBLK + tx;

    {
        int gj = b * M + blockIdx.x * CJ + tx;
        float4 f = p2[gj];
        tile4[tx] = make_float4(f.x, f.y, f.z, c2 * f.w);
    }
    __syncthreads();

    float4 fa = p1[b * N + i0];
    float4 fb = p1[b * N + i0 + TPB];
    float4 fc = p1[b * N + i0 + 2 * TPB];
    float4 fd = p1[b * N + i0 + 3 * TPB];
    const float m2c = -2.0f * c2;
    v2f Xp0 = {m2c * fa.x, m2c * fb.x}, Xp1 = {m2c * fc.x, m2c * fd.x};
    v2f Yp0 = {m2c * fa.y, m2c * fb.y}, Yp1 = {m2c * fc.y, m2c * fd.y};
    v2f Zp0 = {m2c * fa.z, m2c * fb.z}, Zp1 = {m2c * fc.z, m2c * fd.z};
    v2f ni0 = {c2 * fa.w, c2 * fb.w}, ni1 = {c2 * fc.w, c2 * fd.w};

    v2f acc0 = {0.0f, 0.0f}, acc1 = {0.0f, 0.0f};
#pragma unroll 8
    for (int t = 0; t < CJ; ++t) {
        float4 q4 = tile4[t];
        v2f arg0 = q4.x * Xp0 + (q4.y * Yp0 + (q4.z * Zp0 + (ni0 + q4.w)));
        v2f arg1 = q4.x * Xp1 + (q4.y * Yp1 + (q4.z * Zp1 + (ni1 + q4.w)));
        acc0 += exp2v(arg0);
        acc1 += exp2v(arg1);
    }
    atomicAdd(&rs[b * N + i0], acc0.x);
    atomicAdd(&rs[b * N + i0 + TPB], acc0.y);
    atomicAdd(&rs[b * N + i0 + 2 * TPB], acc1.x);
    atomicAdd(&rs[b * N + i0 + 3 * TPB], acc1.y);
}

// ---------------------------------------------------------------------------
// Column sweep (level l) + folded rl-update of level l-1 (tile phase).
// 4 cols/thread as two v2f chains; LDS tiles the rows (a_i).
// ---------------------------------------------------------------------------
__global__ __launch_bounds__(TPB, 2) void k_colsum(const float4* __restrict__ p1,
                                                   const float4* __restrict__ p2,
                                                   const float* __restrict__ rl_in,
                                                   float* __restrict__ rl_out,
                                                   const float* __restrict__ rs_prev,
                                                   const float* __restrict__ rs_cur,
                                                   float* __restrict__ rs_zero,
                                                   const float* __restrict__ t1_in,
                                                   float* __restrict__ t1_zero,
                                                   const float* __restrict__ rr,
                                                   float* __restrict__ ss2_acc,
                                                   float cS) {
    __shared__ float4 tile4[CJ];  // xi, yi, zi, cS*ni
    __shared__ float tileA[CJ];   // a_i
    const int b = blockIdx.z;
    const int tx = threadIdx.x;
    const int j0 = blockIdx.y * RBLK + tx;

    {
        int gi = b * N + blockIdx.x * CJ + tx;
        float4 f = p1[gi];
        float rlo = rl_in[gi];
        float ap = rlo / (rs_prev[gi] + 1e-9f);
        float rln = fmaxf(rlo - ap * t1_in[gi], 0.0f);
        float a = rln / (rs_cur[gi] + 1e-9f);
        tile4[tx] = make_float4(f.x, f.y, f.z, cS * f.w);
        tileA[tx] = a;
        if (blockIdx.y == 0) {
            rl_out[gi] = rln;
            t1_zero[gi] = 0.0f;
            rs_zero[gi] = 0.0f;
        }
    }
    __syncthreads();

    float4 fa = p2[b * M + j0];
    float4 fb = p2[b * M + j0 + TPB];
    float4 fc = p2[b * M + j0 + 2 * TPB];
    float4 fd = p2[b * M + j0 + 3 * TPB];
    const float m2c = -2.0f * cS;
    v2f Xp0 = {m2c * fa.x, m2c * fb.x}, Xp1 = {m2c * fc.x, m2c * fd.x};
    v2f Yp0 = {m2c * fa.y, m2c * fb.y}, Yp1 = {m2c * fc.y, m2c * fd.y};
    v2f Zp0 = {m2c * fa.z, m2c * fb.z}, Zp1 = {m2c * fc.z, m2c * fd.z};
    v2f nj0 = {cS * fa.w, cS * fb.w}, nj1 = {cS * fc.w, cS * fd.w};

    v2f acc0 = {0.0f, 0.0f}, acc1 = {0.0f, 0.0f};
#pragma unroll 8
    for (int t = 0; t < CJ; ++t) {
        float4 q4 = tile4[t];
        float av = tileA[t];
        v2f arg0 = q4.x * Xp0 + (q4.y * Yp0 + (q4.z * Zp0 + (nj0 + q4.w)));
        v2f arg1 = q4.x * Xp1 + (q4.y * Yp1 + (q4.z * Zp1 + (nj1 + q4.w)));
        acc0 += exp2v(arg0) * av;
        acc1 += exp2v(arg1) * av;
    }
    atomicAdd(&ss2_acc[b * M + j0], acc0.x * rr[b * M + j0]);
    atomicAdd(&ss2_acc[b * M + j0 + TPB], acc0.y * rr[b * M + j0 + TPB]);
    atomicAdd(&ss2_acc[b * M + j0 + 2 * TPB], acc1.x * rr[b * M + j0 + 2 * TPB]);
    atomicAdd(&ss2_acc[b * M + j0 + 3 * TPB], acc1.y * rr[b * M + j0 + 3 * TPB]);
}

// ---------------------------------------------------------------------------
// Level-9 colsum, part 1 (exp==1): per-batch S = sum_i a_i + folded rl-update
// of level 8. Grid: B WGs x 256 threads.
// ---------------------------------------------------------------------------
__global__ __launch_bounds__(256) void k_suma(const float* __restrict__ rl_in,
                                              float* __restrict__ rl_out,
                                              const float* __restrict__ rs_prev,
                                              const float* __restrict__ rs_cur,
                                              const float* __restrict__ t1_in,
                                              float* __restrict__ S) {
    __shared__ float red[4];
    const int b = blockIdx.x;
    const int tx = threadIdx.x;
    float s = 0.0f;
#pragma unroll
    for (int k = 0; k < N / 256; ++k) {
        int gi = b * N + k * 256 + tx;
        float rlo = rl_in[gi];
        float ap = rlo / (rs_prev[gi] + 1e-9f);
        float rln = fmaxf(rlo - ap * t1_in[gi], 0.0f);
        rl_out[gi] = rln;
        s += rln / (rs_cur[gi] + 1e-9f);
    }
#pragma unroll
    for (int off = 32; off > 0; off >>= 1)
        s += __shfl_down(s, off, 64);
    if ((tx & 63) == 0) red[tx >> 6] = s;
    __syncthreads();
    if (tx == 0) S[b] = red[0] + red[1] + red[2] + red[3];
}

// Level-9 colsum, part 2: ss2[j] = rr[j] * S[b]  (direct store)
__global__ __launch_bounds__(256) void k_mulss2(const float* __restrict__ rr,
                                                const float* __restrict__ S,
                                                float* __restrict__ ss2_out) {
    int idx = blockIdx.x * 256 + threadIdx.x;
    ss2_out[idx] = rr[idx] * S[idx >> 11];
}

// ---------------------------------------------------------------------------
// Fused finrow(l) + rowsum(l+1). 4 rows/thread as two v2f chains.
// tile elem j: s=min(rr/(ss2+eps),1); q=rr*s; rrn=max(rr-ss2*s,0);
//   duties (y==0): rr_out[j]=rrn, zero ss2_zero[j].
// MODE 0 (l=0..7): cS=c2[l+1]; en=exp2(arg); el=en^4
// MODE 1 (l=8):    cS=c2[8];   el=exp2(arg); en=1
// MODE 2 (l=9):    cS=1 (arg==d2); el=1; no rs/t1/rr_out
// ---------------------------------------------------------------------------
template <int MODE>
__global__ __launch_bounds__(TPB, 2) void k_fused(const float4* __restrict__ p1,
                                                  const float4* __restrict__ p2,
                                                  const float* __restrict__ rr_in,
                                                  float* __restrict__ rr_out,
                                                  const float* __restrict__ ss2_in,
                                                  float* __restrict__ ss2_zero,
                                                  const float* __restrict__ rl_new,
                                                  const float* __restrict__ rs_cur,
                                                  float* __restrict__ rs_next,
                                                  float* __restrict__ t1_acc,
                                                  float* __restrict__ cost,
                                                  float cS, float invS) {
    __shared__ float4 tile4[CJ];  // xj, yj, zj, q
    __shared__ float2 tile2[CJ];  // rrn, cS*nj
    const int b = blockIdx.z;
    const int tx = threadIdx.x;
    const int i0 = blockIdx.y * RBLK + tx;

    {
        int gj = b * M + blockIdx.x * CJ + tx;
        float4 f = p2[gj];
        float rrv = rr_in[gj];
        float sv = ss2_in[gj];
        float s = fminf(rrv / (sv + 1e-9f), 1.0f);
        float q = rrv * s;
        float rrn = fmaxf(rrv - sv * s, 0.0f);
        tile4[tx] = make_float4(f.x, f.y, f.z, q);
        tile2[tx] = make_float2(rrn, cS * f.w);
        if (MODE != 2 && blockIdx.y == 0) {
            rr_out[gj] = rrn;
            ss2_zero[gj] = 0.0f;
        }
    }
    __syncthreads();

    float4 fa = p1[b * N + i0];
    float4 fb = p1[b * N + i0 + TPB];
    float4 fc = p1[b * N + i0 + 2 * TPB];
    float4 fd = p1[b * N + i0 + 3 * TPB];
    const float m2c = -2.0f * cS;
    v2f Xp0 = {m2c * fa.x, m2c * fb.x}, Xp1 = {m2c * fc.x, m2c * fd.x};
    v2f Yp0 = {m2c * fa.y, m2c * fb.y}, Yp1 = {m2c * fc.y, m2c * fd.y};
    v2f Zp0 = {m2c * fa.z, m2c * fb.z}, Zp1 = {m2c * fc.z, m2c * fd.z};
    v2f ni0 = {cS * fa.w, cS * fb.w}, ni1 = {cS * fc.w, cS * fd.w};

    v2f T10 = {0.0f, 0.0f}, T20 = {0.0f, 0.0f}, rs0v = {0.0f, 0.0f};
    v2f T11 = {0.0f, 0.0f}, T21 = {0.0f, 0.0f}, rs1v = {0.0f, 0.0f};
#pragma unroll 8
    for (int t = 0; t < CJ; ++t) {
        float4 q4 = tile4[t];
        float2 rn = tile2[t];
        v2f arg0 = q4.x * Xp0 + (q4.y * Yp0 + (q4.z * Zp0 + (ni0 + rn.y)));
        v2f arg1 = q4.x * Xp1 + (q4.y * Yp1 + (q4.z * Zp1 + (ni1 + rn.y)));
        v2f el0, el1, en0, en1;
        if (MODE == 0) {
            en0 = exp2v(arg0);
            en1 = exp2v(arg1);
            v2f e20 = en0 * en0, e21 = en1 * en1;
            el0 = e20 * e20;
            el1 = e21 * e21;
        } else if (MODE == 1) {
            el0 = exp2v(arg0);
            el1 = exp2v(arg1);
        }
        v2f d20 = arg0 * invS, d21 = arg1 * invS;
        d20.x = fmaxf(d20.x, 1e-12f);
        d20.y = fmaxf(d20.y, 1e-12f);
        d21.x = fmaxf(d21.x, 1e-12f);
        d21.y = fmaxf(d21.y, 1e-12f);
        v2f sd0, sd1;
        sd0.x = SQRTF(d20.x);
        sd0.y = SQRTF(d20.y);
        sd1.x = SQRTF(d21.x);
        sd1.y = SQRTF(d21.y);
        v2f wq0, wq1;
        if (MODE == 2) {
            wq0.x = q4.w; wq0.y = q4.w;
            wq1.x = q4.w; wq1.y = q4.w;
        } else {
            wq0 = el0 * q4.w;
            wq1 = el1 * q4.w;
        }
        T10 += wq0;
        T11 += wq1;
        T20 += wq0 * sd0;
        T21 += wq1 * sd1;
        if (MODE == 0) {
            rs0v += en0 * rn.x;
            rs1v += en1 * rn.x;
        } else if (MODE == 1) {
            rs0v += rn.x;
            rs1v += rn.x;
        }
    }

    const int gi0 = b * N + i0;
    if (MODE != 2) {
        atomicAdd(&t1_acc[gi0], T10.x);
        atomicAdd(&t1_acc[gi0 + TPB], T10.y);
        atomicAdd(&t1_acc[gi0 + 2 * TPB], T11.x);
        atomicAdd(&t1_acc[gi0 + 3 * TPB], T11.y);
        atomicAdd(&rs_next[gi0], rs0v.x);
        atomicAdd(&rs_next[gi0 + TPB], rs0v.y);
        atomicAdd(&rs_next[gi0 + 2 * TPB], rs1v.x);
        atomicAdd(&rs_next[gi0 + 3 * TPB], rs1v.y);
    }

    float aa = rl_new[gi0] / (rs_cur[gi0] + 1e-9f);
    float ab = rl_new[gi0 + TPB] / (rs_cur[gi0 + TPB] + 1e-9f);
    float ac = rl_new[gi0 + 2 * TPB] / (rs_cur[gi0 + 2 * TPB] + 1e-9f);
    float ad = rl_new[gi0 + 3 * TPB] / (rs_cur[gi0 + 3 * TPB] + 1e-9f);
    float contrib = fmaf(aa, T20.x, fmaf(ab, T20.y, fmaf(ac, T21.x, ad * T21.y)));
#pragma unroll
    for (int off = 32; off > 0; off >>= 1)
        contrib += __shfl_down(contrib, off, 64);
    if ((threadIdx.x & 63) == 0) atomicAdd(&cost[b], contrib);
}

extern "C" void kernel_launch(void* const* d_in, const int* in_sizes, int n_in,
                              void* d_out, int out_size, void* d_ws, size_t ws_size,
                              hipStream_t stream) {
    const float* xyz1 = (const float*)d_in[0];
    const float* xyz2 = (const float*)d_in[1];
    float* cost = (float*)d_out;

    float* ws = (float*)d_ws;
    float* rl[2] = {ws + 0 * BN, ws + 1 * BN};
    float* rr[2] = {ws + 2 * BN, ws + 3 * BN};
    float* rs[3] = {ws + 4 * BN, ws + 5 * BN, ws + 6 * BN};
    float* ss2b[2] = {ws + 7 * BN, ws + 8 * BN};
    float* t1[2] = {ws + 9 * BN, ws + 10 * BN};
    float4* p1 = (float4*)(ws + 11 * BN);
    float4* p2 = (float4*)(ws + 15 * BN);
    float* S = ws + 19 * BN;

    static const float levels[10] = {-16384.0f, -4096.0f, -1024.0f, -256.0f,
                                     -64.0f,    -16.0f,   -4.0f,    -1.0f,
                                     -0.25f,    0.0f};
    float c2[10];
    for (int l = 0; l < 10; ++l) c2[l] = levels[l] * LOG2E;

    dim3 grid(NCH, N / RBLK, B);  // (16, 4, 16) = 1024 WGs
    dim3 blk(TPB);

    k_pack<<<dim3(2 * BN / 256), dim3(256), 0, stream>>>(xyz1, xyz2, p1, p2);
    k_init<<<dim3(BN / 256), dim3(256), 0, stream>>>(rl[0], rr[0], rs[0], rs[2],
                                                     t1[1], ss2b[0], cost);
    k_rowsum0<<<grid, blk, 0, stream>>>(p1, p2, rs[0], c2[0]);

    for (int l = 0; l < 10; ++l) {
        int p = l & 1;
        if (l < 9) {
            k_colsum<<<grid, blk, 0, stream>>>(
                p1, p2, rl[p], rl[1 - p], rs[(l + 2) % 3], rs[l % 3],
                rs[(l + 1) % 3], t1[1 - p], t1[p], rr[p], ss2b[p], c2[l]);
        } else {
            k_suma<<<dim3(B), dim3(256), 0, stream>>>(
                rl[p], rl[1 - p], rs[(l + 2) % 3], rs[l % 3], t1[1 - p], S);
            k_mulss2<<<dim3(BN / 256), dim3(256), 0, stream>>>(rr[p], S, ss2b[p]);
        }

        if (l <= 7) {
            float cS = c2[l + 1];
            k_fused<0><<<grid, blk, 0, stream>>>(
                p1, p2, rr[p], rr[1 - p], ss2b[p], ss2b[1 - p], rl[1 - p],
                rs[l % 3], rs[(l + 1) % 3], t1[p], cost, cS, 1.0f / cS);
        } else if (l == 8) {
            float cS = c2[8];
            k_fused<1><<<grid, blk, 0, stream>>>(
                p1, p2, rr[p], rr[1 - p], ss2b[p], ss2b[1 - p], rl[1 - p],
                rs[l % 3], rs[(l + 1) % 3], t1[p], cost, cS, 1.0f / cS);
        } else {
            k_fused<2><<<grid, blk, 0, stream>>>(
                p1, p2, rr[p], rr[1 - p], ss2b[p], ss2b[1 - p], rl[1 - p],
                rs[l % 3], rs[(l + 1) % 3], t1[p], cost, 1.0f, 1.0f);
        }
    }
}